// Round 8
// baseline (455.401 us; speedup 1.0000x reference)
//
#include <hip/hip_runtime.h>

// ---------------------------------------------------------------------------
// QKGainAttention on MI355X (gfx950), round 15.
// R14 postmortem: correctness restored; QKV GEMM at R11 level (130us, 33%).
// Analysis: the 256x192 structure is LDS-READ-bound. Per-FLOP LDS traffic
// ~ 1/Wm+1/Wn; 128x48 waves = 0.0286 vs 128x96 = 0.0182 (-36%). R15: QKV
// as BM=256 BN=384, BK=32 -> grid 16x16 = 256 blocks = 1 round, 8 waves of
// 128x96 (acc[8][6]=192 VGPR), LDS 80KB dbuf. Staging: 5x8KB quarters/tile,
// ALL t+1 stages -> buf^1 (race-free like k_gemm_proj), ONE vmcnt(0)+barrier
// per tile -- no counted-vmcnt bookkeeping. BK=32 needs a new swizzle: rows
// are 64B, so per-row XOR only spreads 4-way. New chunk-major permutation:
// slot = (row>>3)*32 + (k>>3)*8 + (row&7) -> 16-row read hits bank residues
// 0..7 exactly 2x = free. gload_lds dest stays linear; permutation is in the
// per-lane GLOBAL source (both-sides rule). One mfma16(K=32)/acc/tile,
// ascending k = bit-identical accumulation. Everything else R14-unchanged.
// ---------------------------------------------------------------------------

#define DEVINL __device__ __forceinline__

typedef unsigned short u16;
typedef __bf16 bf16x8 __attribute__((ext_vector_type(8)));
typedef float  f32x4  __attribute__((ext_vector_type(4)));
typedef float  f32x16 __attribute__((ext_vector_type(16)));
typedef short  short8 __attribute__((ext_vector_type(8)));
typedef u16    u16x4  __attribute__((ext_vector_type(4)));
typedef unsigned uint4x __attribute__((ext_vector_type(4)));

static constexpr int T_  = 2048;
static constexpr int C_  = 2048;
static constexpr int TC3 = 6144;   // 3*C

DEVINL u16 f2bf(float f) {
  union { float f; unsigned u; } v; v.f = f;
  unsigned r = v.u + 0x7FFFu + ((v.u >> 16) & 1u);   // RNE
  return (u16)(r >> 16);
}
DEVINL float bf2f(u16 s) {
  union { unsigned u; float f; } v; v.u = ((unsigned)s) << 16;
  return v.f;
}
DEVINL bf16x8 ld8(const u16* p) {
  return __builtin_bit_cast(bf16x8, *(const short8*)p);
}
DEVINL f32x4 mfma16(bf16x8 a, bf16x8 b, f32x4 c) {
  return __builtin_amdgcn_mfma_f32_16x16x32_bf16(a, b, c, 0, 0, 0);
}
DEVINL f32x16 mfma32(bf16x8 a, bf16x8 b, f32x16 c) {
  return __builtin_amdgcn_mfma_f32_32x32x16_bf16(a, b, c, 0, 0, 0);
}
DEVINL void async_cp16(const u16* gp, u16* lp) {
  __builtin_amdgcn_global_load_lds(
      (const __attribute__((address_space(1))) void*)gp,
      (__attribute__((address_space(3))) void*)lp, 16, 0, 0);
}
DEVINL unsigned cvtpk(float lo, float hi) {
  unsigned r;
  asm("v_cvt_pk_bf16_f32 %0, %1, %2" : "=v"(r) : "v"(lo), "v"(hi));
  return r;
}
DEVINL void plswap(unsigned& a, unsigned& b) {
  asm("v_permlane32_swap_b32 %0, %1" : "+v"(a), "+v"(b));
}
template<int N> DEVINL void vmwait() {
  if constexpr (N == 0)      asm volatile("s_waitcnt vmcnt(0)" ::: "memory");
}

// ---------------- fused dtype casts (3 inputs, one launch) ----------------
__global__ __launch_bounds__(256) void k_cast_all(
    const float* __restrict__ x, const int* __restrict__ aw,
    const int* __restrict__ pw, u16* __restrict__ xb,
    u16* __restrict__ wab, u16* __restrict__ wpb) {
  const int b = blockIdx.x;
  if (b < 8192) {
    long i = (long)(b * 256 + threadIdx.x) * 4;
    float4 v = *(const float4*)(x + i);
    u16x4 o; o.x = f2bf(v.x); o.y = f2bf(v.y); o.z = f2bf(v.z); o.w = f2bf(v.w);
    *(u16x4*)(xb + i) = o;
  } else {
    const int* in; u16* out; int lb;
    if (b < 20480) { in = aw; out = wab; lb = b - 8192; }
    else           { in = pw; out = wpb; lb = b - 20480; }
    long i = (long)(lb * 256 + threadIdx.x) * 4;
    int4 v = *(const int4*)(in + i);
    u16x4 o; o.x = f2bf((float)v.x); o.y = f2bf((float)v.y);
    o.z = f2bf((float)v.z); o.w = f2bf((float)v.w);
    *(u16x4*)(out + i) = o;
  }
}

// ---------------- GEMM 256x384 1-round, BK=32, chunk-major LDS (QKV) --------
// LDS per buffer: As [256 rows][32 k], Bs [384][32] bf16, stored chunk-major
// within 8-row groups: 16B-slot pos = (row>>3)*32 + (k>>3)*8 + (row&7).
// A 16-lane frag read (rows R0..R0+15, fixed k-chunk) hits slot residues
// mod 8 = row&7 -> each bank-group exactly 2x = conflict-free.
// Staging quarter = 128 rows = 8KB = 512 thr x 16B, linear LDS dest; the
// chunk-major permutation is applied to the per-lane GLOBAL source address.
template<int SZ>
DEVINL void stage32(const u16* __restrict__ G, long brow, long K, int tt, int qi,
                    u16 (&L)[2][SZ], int w, int lane) {
  const int p  = w * 64 + lane;            // slot id 0..511 within quarter
  const int r8 = p & 7;                    // row low bits
  const int ck = (p >> 3) & 3;             // k-chunk (8 bf16 = 16B)
  const int q  = p >> 5;                   // 8-row group 0..15
  const long row = brow + qi * 128 + q * 8 + r8;
  async_cp16(G + row * K + (long)(tt << 5) + ck * 8,
             &L[tt & 1][(qi * 512 + w * 64) * 8]);
}

__global__ __launch_bounds__(512, 2) void k_gemm256(
    const u16* __restrict__ A, const u16* __restrict__ Bt,
    const float* __restrict__ scale, u16* __restrict__ C,
    int N, long K) {
  __shared__ u16 As[2][256 * 32];
  __shared__ u16 Bs[2][384 * 32];
  const int tid = threadIdx.x, w = tid >> 6, lane = tid & 63;
  const int l15 = lane & 15, quad = lane >> 4;
  const int wm = (w & 1) * 128;            // wave tile 128x96
  const int wn = (w >> 1) * 96;
  const long bm = (long)blockIdx.y * 256;
  const long bn = (long)blockIdx.x * 384;
  const int nt = (int)(K >> 5);            // K-tiles of 32 (=64 here)

  // frag read: row = base + mi*16 + l15, k-chunk = quad.
  // pos = ((base>>3) + mi*2 + (l15>>3))*32 + quad*8 + (l15&7); u16 = pos*8.
  const int abase = ((wm >> 3) + (l15 >> 3)) * 32 + quad * 8 + (l15 & 7);
  const int bbase = ((wn >> 3) + (l15 >> 3)) * 32 + quad * 8 + (l15 & 7);

  // prologue: tile0's 5 quarters (A:2, B:3), full drain
  stage32(A,  bm, K, 0, 0, As, w, lane); stage32(A,  bm, K, 0, 1, As, w, lane);
  stage32(Bt, bn, K, 0, 0, Bs, w, lane); stage32(Bt, bn, K, 0, 1, Bs, w, lane);
  stage32(Bt, bn, K, 0, 2, Bs, w, lane);
  vmwait<0>();
  __builtin_amdgcn_s_barrier();

  f32x4 acc[8][6] = {};
  for (int t = 0; t < nt; ++t) {
    const int buf = t & 1;
    const bool iss = (t < nt - 1);
    bf16x8 bfr[6], afr[4];

    // ---- P0: stage (t+1).Aq0,Aq1,Bq0 -> buf^1; read B(6)+A-lo(4); MFMA ----
    if (iss) {
      stage32(A,  bm, K, t + 1, 0, As, w, lane);
      stage32(A,  bm, K, t + 1, 1, As, w, lane);
      stage32(Bt, bn, K, t + 1, 0, Bs, w, lane);
    }
#pragma unroll
    for (int ni = 0; ni < 6; ++ni) bfr[ni] = ld8(&Bs[buf][(bbase + ni * 64) * 8]);
#pragma unroll
    for (int mi = 0; mi < 4; ++mi) afr[mi] = ld8(&As[buf][(abase + mi * 64) * 8]);
    __builtin_amdgcn_s_barrier();
    __builtin_amdgcn_s_setprio(1);
#pragma unroll
    for (int mi = 0; mi < 4; ++mi)
#pragma unroll
      for (int ni = 0; ni < 6; ++ni)
        acc[mi][ni] = mfma16(afr[mi], bfr[ni], acc[mi][ni]);
    __builtin_amdgcn_s_setprio(0);
    __builtin_amdgcn_s_barrier();

    // ---- P1: stage (t+1).Bq1,Bq2; read A-hi(4); MFMA; end-of-tile drain ----
    if (iss) {
      stage32(Bt, bn, K, t + 1, 1, Bs, w, lane);
      stage32(Bt, bn, K, t + 1, 2, Bs, w, lane);
    }
#pragma unroll
    for (int mi = 0; mi < 4; ++mi) afr[mi] = ld8(&As[buf][(abase + (4 + mi) * 64) * 8]);
    __builtin_amdgcn_s_barrier();
    __builtin_amdgcn_s_setprio(1);
#pragma unroll
    for (int mi = 0; mi < 4; ++mi)
#pragma unroll
      for (int ni = 0; ni < 6; ++ni)
        acc[4 + mi][ni] = mfma16(afr[mi], bfr[ni], acc[4 + mi][ni]);
    __builtin_amdgcn_s_setprio(0);
    if (iss) {
      vmwait<0>();                         // t+1's 5 quarters landed
      __builtin_amdgcn_s_barrier();
    }
  }

  // ---- epilogue: bf16 out with per-col scale ----
#pragma unroll
  for (int ni = 0; ni < 6; ++ni) {
    const long col = bn + wn + ni * 16 + l15;
    const float sc = scale[col];
#pragma unroll
    for (int mi = 0; mi < 8; ++mi) {
      const long row0 = bm + wm + mi * 16 + quad * 4;
#pragma unroll
      for (int r = 0; r < 4; ++r)
        C[(row0 + r) * (long)N + col] = f2bf(acc[mi][ni][r] * sc);
    }
  }
}

// ---------------- GEMM 128x256 1-round (proj), f32 out ----------------------
// Grid 8x32 = 256 blocks = exactly 1 round. 512thr, 8 waves of 64x64,
// acc[4][4]. LDS 96KB. Row-major [row][64] with per-row XOR swizzle
// (k ^ ((row&7)*8)); stages -> buf^1; ONE vmcnt(0)+barrier per tile.
template<int SZ>
DEVINL void stage_q(const u16* __restrict__ G, long brow, long K, int tt, int qi,
                    u16 (&L)[2][SZ], int w, int lane) {
  const int sr = w * 8 + (lane >> 3);      // row within quarter
  const int sc = lane & 7;                 // 16B chunk
  const long grow = brow + qi * 64 + sr;
  async_cp16(G + grow * K + (long)(tt << 6) + ((sc ^ (sr & 7)) << 3),
             &L[tt & 1][(qi * 64 + w * 8) * 64]);
}

__global__ __launch_bounds__(512, 2) void k_gemm_proj(
    const u16* __restrict__ A, const u16* __restrict__ Bt,
    const float* __restrict__ scale, float* __restrict__ C,
    int N, long K) {
  __shared__ u16 As[2][128 * 64];
  __shared__ u16 Bs[2][256 * 64];
  const int tid = threadIdx.x, w = tid >> 6, lane = tid & 63;
  const int l15 = lane & 15, quad = lane >> 4;
  const int wm = (w & 1) * 64, wn = (w >> 1) * 64;
  const long bm = (long)blockIdx.y * 128;
  const long bn = (long)blockIdx.x * 256;
  const int nt = (int)(K >> 6);

  auto rdA = [&](int mi, int kc, int buf) -> bf16x8 {
    const int row = wm + mi * 16 + l15;
    const int k0 = kc * 32 + quad * 8;
    return ld8(&As[buf][row * 64 + (k0 ^ ((row & 7) * 8))]);
  };
  auto rdB = [&](int ni, int kc, int buf) -> bf16x8 {
    const int row = wn + ni * 16 + l15;
    const int k0 = kc * 32 + quad * 8;
    return ld8(&Bs[buf][row * 64 + (k0 ^ ((row & 7) * 8))]);
  };

  // prologue: tile0's 6 quarters, full drain
  stage_q(A, bm, K, 0, 0, As, w, lane); stage_q(A, bm, K, 0, 1, As, w, lane);
  stage_q(Bt, bn, K, 0, 0, Bs, w, lane); stage_q(Bt, bn, K, 0, 1, Bs, w, lane);
  stage_q(Bt, bn, K, 0, 2, Bs, w, lane); stage_q(Bt, bn, K, 0, 3, Bs, w, lane);
  vmwait<0>();
  __builtin_amdgcn_s_barrier();

  f32x4 acc[4][4] = {};
  for (int t = 0; t < nt; ++t) {
    const int buf = t & 1;
    const bool iss = (t < nt - 1);
    bf16x8 a01[2][2], a23[2][2], b01[2][2], b23[2][2];

    // ---- P0: stage (t+1).Bq0,Bq1,Aq0; read a01(4)+b01(4); MFMA Q00 ----
    if (iss) {
      stage_q(Bt, bn, K, t + 1, 0, Bs, w, lane);
      stage_q(Bt, bn, K, t + 1, 1, Bs, w, lane);
      stage_q(A,  bm, K, t + 1, 0, As, w, lane);
    }
#pragma unroll
    for (int mi = 0; mi < 2; ++mi) { a01[mi][0] = rdA(mi, 0, buf); a01[mi][1] = rdA(mi, 1, buf); }
#pragma unroll
    for (int ni = 0; ni < 2; ++ni) { b01[ni][0] = rdB(ni, 0, buf); b01[ni][1] = rdB(ni, 1, buf); }
    __builtin_amdgcn_s_barrier();
    __builtin_amdgcn_s_setprio(1);
#pragma unroll
    for (int mi = 0; mi < 2; ++mi)
#pragma unroll
      for (int ni = 0; ni < 2; ++ni) {
        acc[mi][ni] = mfma16(a01[mi][0], b01[ni][0], acc[mi][ni]);
        acc[mi][ni] = mfma16(a01[mi][1], b01[ni][1], acc[mi][ni]);
      }
    __builtin_amdgcn_s_setprio(0);
    __builtin_amdgcn_s_barrier();

    // ---- P1: stage (t+1).Bq2,Bq3,Aq1; read b23(4); MFMA Q01 ----
    if (iss) {
      stage_q(Bt, bn, K, t + 1, 2, Bs, w, lane);
      stage_q(Bt, bn, K, t + 1, 3, Bs, w, lane);
      stage_q(A,  bm, K, t + 1, 1, As, w, lane);
    }
#pragma unroll
    for (int ni = 0; ni < 2; ++ni) { b23[ni][0] = rdB(2 + ni, 0, buf); b23[ni][1] = rdB(2 + ni, 1, buf); }
    __builtin_amdgcn_s_barrier();
    __builtin_amdgcn_s_setprio(1);
#pragma unroll
    for (int mi = 0; mi < 2; ++mi)
#pragma unroll
      for (int ni = 0; ni < 2; ++ni) {
        acc[mi][2 + ni] = mfma16(a01[mi][0], b23[ni][0], acc[mi][2 + ni]);
        acc[mi][2 + ni] = mfma16(a01[mi][1], b23[ni][1], acc[mi][2 + ni]);
      }
    __builtin_amdgcn_s_setprio(0);
    __builtin_amdgcn_s_barrier();

    // ---- P2: read a23(4); MFMA Q11 ----
#pragma unroll
    for (int mi = 0; mi < 2; ++mi) { a23[mi][0] = rdA(2 + mi, 0, buf); a23[mi][1] = rdA(2 + mi, 1, buf); }
    __builtin_amdgcn_s_barrier();
    __builtin_amdgcn_s_setprio(1);
#pragma unroll
    for (int mi = 0; mi < 2; ++mi)
#pragma unroll
      for (int ni = 0; ni < 2; ++ni) {
        acc[2 + mi][2 + ni] = mfma16(a23[mi][0], b23[ni][0], acc[2 + mi][2 + ni]);
        acc[2 + mi][2 + ni] = mfma16(a23[mi][1], b23[ni][1], acc[2 + mi][2 + ni]);
      }
    __builtin_amdgcn_s_setprio(0);
    __builtin_amdgcn_s_barrier();

    // ---- P3: MFMA Q10; end-of-tile drain (skipped on last) ----
    __builtin_amdgcn_s_setprio(1);
#pragma unroll
    for (int mi = 0; mi < 2; ++mi)
#pragma unroll
      for (int ni = 0; ni < 2; ++ni) {
        acc[2 + mi][ni] = mfma16(a23[mi][0], b01[ni][0], acc[2 + mi][ni]);
        acc[2 + mi][ni] = mfma16(a23[mi][1], b01[ni][1], acc[2 + mi][ni]);
      }
    __builtin_amdgcn_s_setprio(0);
    if (iss) {
      vmwait<0>();
      __builtin_amdgcn_s_barrier();
    }
  }

  // ---- epilogue: f32 out with per-col scale ----
#pragma unroll
  for (int ni = 0; ni < 4; ++ni) {
    const long col = bn + wn + ni * 16 + l15;
    const float sc = scale[col];
#pragma unroll
    for (int mi = 0; mi < 4; ++mi) {
      const long row0 = bm + wm + mi * 16 + quad * 4;
#pragma unroll
      for (int r = 0; r < 4; ++r)
        C[(row0 + r) * (long)N + col] = acc[mi][ni][r] * sc;
    }
  }
}

// ---------------- fused l2norm(q,k) + V transpose (disjoint regions) --------
__global__ __launch_bounds__(256) void k_norm_vt(u16* __restrict__ qkv,
                                                 const float* __restrict__ qk_gain,
                                                 u16* __restrict__ vt) {
  const int b = blockIdx.x;
  if (b < 4096) {
    // l2norm(q,k); fold qk_gain^2*log2e/sqrt(HD) into q
    const int token = b;
    const int wave = threadIdx.x >> 6, lane = threadIdx.x & 63;
    const float g = qk_gain[0];
    const float qmul = g * g * 1.44269504f * 0.08838834764f;
    u16* rowp = qkv + (long)token * TC3;
#pragma unroll
    for (int s = 0; s < 8; ++s) {
      const int seg = wave * 8 + s;
      const int isK = seg >> 4;
      const int h = seg & 15;
      u16* ptr = rowp + isK * C_ + h * 128 + lane * 2;
      unsigned pv = *(const unsigned*)ptr;
      float a = bf2f((u16)(pv & 0xffffu));
      float bb = bf2f((u16)(pv >> 16));
      float ss = a * a + bb * bb;
#pragma unroll
      for (int m = 1; m <= 32; m <<= 1) ss += __shfl_xor(ss, m);
      float denom = fmaxf(sqrtf(ss), 1e-12f);
      float f = (isK ? 1.0f : qmul) / denom;
      u16 o0 = f2bf(a * f), o1 = f2bf(bb * f);
      *(unsigned*)ptr = (unsigned)o0 | ((unsigned)o1 << 16);
    }
  } else {
    // V transpose: qkv V block -> Vt_g[bz][h][d][t]
    const int v = b - 4096;
    const int t0 = (v & 31) * 64;
    const int h = (v >> 5) & 15;
    const int bz = v >> 9;
    const int t = threadIdx.x & 63;
    const int d0 = threadIdx.x >> 6;       // 0..3
    const long tokbase = (long)bz * T_;
    const u16* src = qkv + (tokbase + t0 + t) * (long)TC3 + 2 * C_ + h * 128;
    u16* dst = vt + ((long)(bz * 16 + h) * 128) * (long)T_ + t0 + t;
#pragma unroll
    for (int dd = 0; dd < 32; ++dd) {
      const int d = dd * 4 + d0;
      dst[(long)d * T_] = src[d];
    }
  }
}

// ---------------- flash attention (causal), m=0 softmax, 32x32 MFMA ---------
__global__ __launch_bounds__(256, 2) void k_attn(const u16* __restrict__ qkv,
                                                 const u16* __restrict__ vtg,
                                                 u16* __restrict__ y) {
  const int qt = blockIdx.z ? (15 - blockIdx.x) : blockIdx.x;
  const int h  = blockIdx.y;
  const int bz = blockIdx.z;
  const int tid = threadIdx.x, w = tid >> 6, lane = tid & 63;
  const int m31 = lane & 31, hi = lane >> 5;

  __shared__ u16 Ks[2][64 * 128];
  __shared__ u16 Vt[2][128 * 64];

  const long tokbase = (long)bz * T_;
  const int qbase = qt * 128 + w * 32;     // 32 queries per wave
  const u16* vbase = vtg + ((long)(bz * 16 + h) * 128) * (long)T_;
  const u16* kbase = qkv + tokbase * TC3 + C_ + h * 128;

  // Q B-frags (32x32x16: col=lane&31=query, k=d=kc*16+hi*8+i)
  bf16x8 qf[8];
  {
    const u16* qp = qkv + (tokbase + qbase + m31) * (long)TC3 + h * 128 + hi * 8;
#pragma unroll
    for (int kc = 0; kc < 8; ++kc)
      qf[kc] = ld8(qp + kc * 16);
  }

  f32x16 o[4];                             // O^T: d=db*32+crow(reg,hi), q=m31
#pragma unroll
  for (int i = 0; i < 4; ++i)
#pragma unroll
    for (int r = 0; r < 16; ++r) o[i][r] = 0.f;
  f32x4 lacc = {0.f, 0.f, 0.f, 0.f};       // per-lane partial row sums (m==0)

  auto stage = [&](int ktb, int b2) {
#pragma unroll
    for (int j = 0; j < 4; ++j) {
      const int t = w * 4 + j;
      const int p = t * 64 + lane;
      const int r  = p >> 4, ck = p & 15;          // K: row r, chunk ck
      async_cp16(kbase + (long)(ktb + r) * TC3 + ((ck ^ (r & 15)) * 8),
                 &Ks[b2][t * 512]);
      const int d  = p >> 3, cv = p & 7;           // V: row d, chunk cv
      async_cp16(vbase + (long)d * T_ + ktb + ((cv ^ (d & 7)) * 8),
                 &Vt[b2][t * 512]);
    }
  };

  stage(0, 0);
  __syncthreads();                         // drain tile-0 staging
  int b = 0;
  const int ktmax = 2 * qt + 1;

  for (int kt = 0; kt <= ktmax; ++kt) {
    const int ktb = kt * 64;
    if (kt < ktmax) stage(ktb + 64, b ^ 1);

    if (ktb <= qbase + 31) {               // skip fully-masked tiles
      // --- S^T = K.Q^T (32x32x16): C frag key=kb*32+crow, query=m31 ---
      f32x16 sA[2];
      __builtin_amdgcn_s_setprio(1);
#pragma unroll
      for (int kb = 0; kb < 2; ++kb) {
        f32x16 acc;
#pragma unroll
        for (int r = 0; r < 16; ++r) acc[r] = 0.f;
#pragma unroll
        for (int kc = 0; kc < 8; ++kc) {
          bf16x8 kf = ld8(&Ks[b][(kb * 32 + m31) * 128 +
                                 (((2 * kc + hi) ^ (lane & 15)) * 8)]);
          acc = mfma32(kf, qf[kc], acc);
        }
        sA[kb] = acc;
      }
      __builtin_amdgcn_s_setprio(0);

      // --- causal mask (one tile per wave hits this) ---
      if (ktb + 63 > qbase) {
        const int qq = qbase + m31;
#pragma unroll
        for (int kb = 0; kb < 2; ++kb)
#pragma unroll
          for (int r = 0; r < 16; ++r) {
            const int key = ktb + kb * 32 + (r & 3) + 8 * (r >> 2) + 4 * hi;
            if (key > qq) sA[kb][r] = -1e30f;
          }
      }
      // --- m=0 softmax: P = exp2(s), 4-way partial sum chains ---
#pragma unroll
      for (int kb = 0; kb < 2; ++kb)
#pragma unroll
        for (int r = 0; r < 16; ++r) {
          float p = __builtin_amdgcn_exp2f(sA[kb][r]);
          sA[kb][r] = p;
          lacc[r & 3] += p;
        }

      // --- P^T B-frags via cvt_pk + permlane32_swap (pure VALU) ---
      bf16x8 pb[4];
#pragma unroll
      for (int ks = 0; ks < 4; ++ks) {
        const int kb = ks >> 1, j = ks & 1;
        unsigned w0a = cvtpk(sA[kb][8 * j + 0], sA[kb][8 * j + 1]);
        unsigned w1a = cvtpk(sA[kb][8 * j + 2], sA[kb][8 * j + 3]);
        unsigned w0b = cvtpk(sA[kb][8 * j + 4], sA[kb][8 * j + 5]);
        unsigned w1b = cvtpk(sA[kb][8 * j + 6], sA[kb][8 * j + 7]);
        plswap(w0a, w0b);                  // w0a=word0, w0b=word2
        plswap(w1a, w1b);                  // w1a=word1, w1b=word3
        uint4x t; t.x = w0a; t.y = w1a; t.z = w0b; t.w = w1b;
        pb[ks] = __builtin_bit_cast(bf16x8, t);
      }

      // --- O^T += V^T.P^T: A=V^T rows d, k=keys ks*16+hi*8+i ---
      __builtin_amdgcn_s_setprio(1);
#pragma unroll
      for (int db = 0; db < 4; ++db)
#pragma unroll
        for (int ks = 0; ks < 4; ++ks) {
          bf16x8 vf = ld8(&Vt[b][(db * 32 + m31) * 64 +
                                 (((2 * ks + hi) ^ (m31 & 7)) * 8)]);
          o[db] = mfma32(vf, pb[ks], o[db]);
        }
      __builtin_amdgcn_s_setprio(0);
    }

    if (kt < ktmax) __syncthreads();       // drains prefetch + guards buffers
    b ^= 1;
  }

  // --- epilogue: l = sum over both lane halves; write O^T ---
  float lrow = lacc[0] + lacc[1] + lacc[2] + lacc[3];
  lrow += __shfl_xor(lrow, 32);
  const float inv_l = 1.0f / lrow;
  u16* yp = y + (tokbase + qbase + m31) * (long)C_ + h * 128 + 4 * hi;
#pragma unroll
  for (int db = 0; db < 4; ++db)
#pragma unroll
    for (int g = 0; g < 4; ++g) {
      u16x4 pk;
#pragma unroll
      for (int r = 0; r < 4; ++r) pk[r] = f2bf(o[db][g * 4 + r] * inv_l);
      *(u16x4*)(yp + db * 32 + g * 8) = pk;
    }
}

// ---------------------------------------------------------------------------
extern "C" void kernel_launch(void* const* d_in, const int* in_sizes, int n_in,
                              void* d_out, int out_size, void* d_ws, size_t ws_size,
                              hipStream_t stream) {
  const float* x    = (const float*)d_in[0];
  const int*   aw   = (const int*)d_in[1];
  const float* asc  = (const float*)d_in[2];
  const int*   pw   = (const int*)d_in[3];
  const float* psc  = (const float*)d_in[4];
  const float* gain = (const float*)d_in[5];

  char* ws = (char*)d_ws;
  u16* xb  = (u16*)(ws);                         // 16.78 MB (reused as Vt_g)
  u16* wab = (u16*)(ws + 16777216UL);
  u16* wpb = (u16*)(ws + 41943040UL);
  u16* qkv = (u16*)(ws + 50331648UL);
  u16* yb  = (u16*)(ws + 100663296UL);
  u16* vtg = xb;                                 // x_bf16 dead after QKV GEMM

  k_cast_all<<<24576, 256, 0, stream>>>(x, aw, pw, xb, wab, wpb);
  k_gemm256<<<dim3(16, 16), 512, 0, stream>>>(xb, wab, asc, qkv, TC3, (long)C_);
  k_norm_vt<<<5120, 256, 0, stream>>>(qkv, gain, vtg);
  k_attn<<<dim3(16, 16, 2), 256, 0, stream>>>(qkv, vtg, yb);
  k_gemm_proj<<<dim3(8, 32), 512, 0, stream>>>(yb, wpb, psc, (float*)d_out, C_, (long)C_);
}